// Round 7
// baseline (2023.546 us; speedup 1.0000x reference)
//
#include <hip/hip_runtime.h>

typedef unsigned int u32;
typedef unsigned short u16;
typedef short s16x8 __attribute__((ext_vector_type(8)));
typedef __bf16 bf16x8 __attribute__((ext_vector_type(8)));
typedef float f32x4 __attribute__((ext_vector_type(4)));

#define KEYMASK 0x7fffffffu
#define CANDCAP 65536
#define TIECAP 2048

__device__ __forceinline__ u16 f2bf(float f) {
  u32 u = __builtin_bit_cast(u32, f);
  return (u16)((u + 0x7fffu + ((u >> 16) & 1u)) >> 16);
}

// Handles either builtin signature (short8 or __bf16x8) across ROCm versions.
struct ABFrag {
  s16x8 v;
  __device__ operator s16x8() const { return v; }
  __device__ operator bf16x8() const { return __builtin_bit_cast(bf16x8, v); }
};

__device__ __forceinline__ f32x4 mfma_bf16(s16x8 a, s16x8 b, f32x4 c) {
  return __builtin_amdgcn_mfma_f32_16x16x32_bf16(ABFrag{a}, ABFrag{b}, c, 0, 0, 0);
}

__device__ __forceinline__ void async16(void* lds, const void* g) {
  __builtin_amdgcn_global_load_lds(
      (__attribute__((address_space(1))) void*)(const_cast<void*>(g)),
      (__attribute__((address_space(3))) void*)lds, 16, 0, 0);
}

// ================= single-pass 20-bit selection =================
// meta per layer (8 u32): [0]=t20 (20-bit prefix threshold bin) [1]=r2 (rank
// within bin) [4]=candCount.
// key = |s| bits (31b, monotone). p20 = key>>11. Zero the n/2 smallest keys.

// One pass: 20-bit prefix histogram via global atomics (3 x 1M u32 bins,
// max bin ~2k hits -> negligible same-address contention) + fused x->bf16.
__global__ void hist20_k(const float4* __restrict__ x, ushort4* __restrict__ xb, int xn4,
                         const uint4* __restrict__ sa, int na,
                         const uint4* __restrict__ sb, int nb,
                         const uint4* __restrict__ sc, int nc,
                         u32* __restrict__ gh) {
  int stride = gridDim.x * blockDim.x;
  // fused convert (independent streaming work)
  for (int i = blockIdx.x * blockDim.x + threadIdx.x; i < xn4; i += stride) {
    float4 v = x[i];
    ushort4 o;
    o.x = f2bf(v.x); o.y = f2bf(v.y); o.z = f2bf(v.z); o.w = f2bf(v.w);
    xb[i] = o;
  }
  const uint4* sp[3] = {sa, sb, sc};
  int nn[3] = {na, nb, nc};
  for (int l = 0; l < 3; ++l) {
    const uint4* s = sp[l];
    int n4 = nn[l];
    u32* hl = gh + ((size_t)l << 20);
    for (int i = blockIdx.x * blockDim.x + threadIdx.x; i < n4; i += stride) {
      uint4 v = s[i];
      atomicAdd(&hl[(v.x & KEYMASK) >> 11], 1u);
      atomicAdd(&hl[(v.y & KEYMASK) >> 11], 1u);
      atomicAdd(&hl[(v.z & KEYMASK) >> 11], 1u);
      atomicAdd(&hl[(v.w & KEYMASK) >> 11], 1u);
    }
  }
}

// One block per layer: find bin T with cumulative crossing rank, residual r2.
__global__ void select20_k(const u32* __restrict__ gh, u32* __restrict__ meta,
                           u32 r0, u32 r1, u32 r2in) {
  const int l = blockIdx.x;
  const u32* hl = gh + ((size_t)l << 20);
  __shared__ u32 part[1024];
  __shared__ u32 binbuf[1024];
  __shared__ u32 csel, rrs;
  int tid = threadIdx.x;
  // per-thread contiguous 1024-bin chunk sum (uint4 loads, L2/L3-hot)
  const uint4* mv = (const uint4*)(hl + (size_t)tid * 1024);
  u32 sm = 0;
  for (int j = 0; j < 256; ++j) { uint4 v = mv[j]; sm += v.x + v.y + v.z + v.w; }
  part[tid] = sm;
  __syncthreads();
  if (tid == 0) {
    u32 r = (l == 0 ? r0 : (l == 1 ? r1 : r2in));
    u32 c = 0; int t = 0;
    for (; t < 1024; ++t) { if (c + part[t] > r) break; c += part[t]; }
    csel = (u32)t; rrs = r - c;
  }
  __syncthreads();
  u32 c0 = csel;
  binbuf[tid] = hl[(size_t)c0 * 1024 + tid];   // cooperative chunk reload
  __syncthreads();
  if (tid == 0) {
    u32 rr = rrs;
    int bin = 0;
    for (;;) { u32 hv = binbuf[bin]; if (rr < hv) break; rr -= hv; ++bin; }
    meta[l * 8 + 0] = c0 * 1024 + (u32)bin;   // t20
    meta[l * 8 + 1] = rr;                     // rank within bin
  }
}

// Fused mask+cast build: p20 > t20 -> bf16(w); < -> 0; == -> 0 + candidate.
// i in [n4, n4pad): write zeros (pad rows for the N=1000->1024 GEMM).
__global__ void build_k(const float4* __restrict__ w, const uint4* __restrict__ s,
                        ushort4* __restrict__ wb, int n4, int n4pad,
                        u32* __restrict__ meta, uint2* __restrict__ cand) {
  u32 t20 = meta[0];
  int stride = gridDim.x * blockDim.x;
  for (int i = blockIdx.x * blockDim.x + threadIdx.x; i < n4pad; i += stride) {
    if (i >= n4) { wb[i] = make_ushort4(0, 0, 0, 0); continue; }
    uint4 sv = s[i];
    float4 wv = w[i];
    u32 k0 = sv.x & KEYMASK, k1 = sv.y & KEYMASK, k2 = sv.z & KEYMASK, k3 = sv.w & KEYMASK;
    ushort4 o;
    o.x = ((k0 >> 11) > t20) ? f2bf(wv.x) : (u16)0;
    o.y = ((k1 >> 11) > t20) ? f2bf(wv.y) : (u16)0;
    o.z = ((k2 >> 11) > t20) ? f2bf(wv.z) : (u16)0;
    o.w = ((k3 >> 11) > t20) ? f2bf(wv.w) : (u16)0;
    wb[i] = o;
    u32 base = (u32)i * 4u;
    if ((k0 >> 11) == t20) { u32 p = atomicAdd(&meta[4], 1u); if (p < CANDCAP) cand[p] = make_uint2(k0, base); }
    if ((k1 >> 11) == t20) { u32 p = atomicAdd(&meta[4], 1u); if (p < CANDCAP) cand[p] = make_uint2(k1, base + 1u); }
    if ((k2 >> 11) == t20) { u32 p = atomicAdd(&meta[4], 1u); if (p < CANDCAP) cand[p] = make_uint2(k2, base + 2u); }
    if ((k3 >> 11) == t20) { u32 p = atomicAdd(&meta[4], 1u); if (p < CANDCAP) cand[p] = make_uint2(k3, base + 3u); }
  }
}

// Exact low-11-bit select among candidates + stable-argsort tie semantics:
// zero the r2 smallest by (k11, flat idx); restore the rest to bf16(w).
__global__ void finalize_k(u16* __restrict__ wb, const float* __restrict__ w,
                           const u32* __restrict__ meta, const uint2* __restrict__ cand) {
  __shared__ u32 h[2048];
  __shared__ u32 tie[TIECAP];
  __shared__ u32 tcnt, t11s, qs;
  int tid = threadIdx.x;
  for (int i = tid; i < 2048; i += blockDim.x) h[i] = 0;
  if (tid == 0) tcnt = 0;
  __syncthreads();
  u32 m = meta[4]; if (m > CANDCAP) m = CANDCAP;
  for (u32 i = tid; i < m; i += blockDim.x) atomicAdd(&h[cand[i].x & 0x7ffu], 1u);
  __syncthreads();
  if (tid == 0) {
    u32 r = meta[1];
    u32 c = 0; int bin = 0;
    for (;;) { u32 hv = h[bin]; if (c + hv > r) break; c += hv; ++bin; }
    t11s = (u32)bin; qs = r - c;
  }
  __syncthreads();
  u32 t11 = t11s, q = qs;
  for (u32 i = tid; i < m; i += blockDim.x) {
    uint2 cd = cand[i];
    u32 k11 = cd.x & 0x7ffu;
    if (k11 > t11) wb[cd.y] = f2bf(w[cd.y]);
    else if (k11 == t11) { u32 p = atomicAdd(&tcnt, 1u); if (p < TIECAP) tie[p] = cd.y; }
  }
  __syncthreads();
  u32 tc = tcnt; if (tc > TIECAP) tc = TIECAP;
  for (u32 i = tid; i < tc; i += blockDim.x) {
    u32 my = tie[i];
    u32 rk = 0;
    for (u32 j = 0; j < tc; ++j) rk += (tie[j] < my) ? 1u : 0u;
    if (rk >= q) wb[my] = f2bf(w[my]);
  }
}

// ======== 256x256 GEMM, BK=64, 8 waves, 4-phase counted-vmcnt pipeline ========
// R4 schedule (best measured: 128.6us/45% on 4096^3) — verbatim revert.
// A LDS: chunk q = LDS rows q*64.., global rows half*128+q*32+r. B: 4 col chunks.
// XOR-swizzle per 16B granule (g^(R&7)); linear LDS dest + inverse-swizzled src.
// Stage: ph0: A3(t+1)->p^1 | ph1: A0,B0(t+2) | ph2: A1,B1 | ph3: A2,B2,B3.
// Waits: vmcnt(8)@ph0 (tile t minus A3 landed), vmcnt(12)@ph3 (A3(t) landed).
__global__ __launch_bounds__(512) void gemm256(
    const u16* __restrict__ A, const u16* __restrict__ B,
    const float* __restrict__ bias, u16* __restrict__ C,
    int N, int K) {
  __shared__ __align__(16) u16 As[2][256 * 64];
  __shared__ __align__(16) u16 Bs[2][256 * 64];
  const int tid = threadIdx.x;
  const int lane = tid & 63;
  const int wv = tid >> 6;
  const int wm = wv >> 2;        // 0..1
  const int wn = wv & 3;         // 0..3
  const int fr = lane & 15;
  const int fkg = lane >> 4;     // 0..3
  const long brow = (long)blockIdx.y * 256;
  const long bcol = (long)blockIdx.x * 256;

  const int sr6 = tid >> 3;                       // 0..63
  const int sgr = ((tid & 7) ^ (sr6 & 7)) << 3;   // inverse-swizzled src elem offset
  const int ha = tid >> 8;                        // A half (0/1)
  const int ra = sr6 & 31;                        // A row within quarter
  const u16* pAq[4];
  const u16* pBc[4];
#pragma unroll
  for (int q = 0; q < 4; ++q)
    pAq[q] = A + (size_t)(brow + ha * 128 + q * 32 + ra) * (size_t)K + sgr;
#pragma unroll
  for (int c = 0; c < 4; ++c)
    pBc[c] = B + (size_t)(bcol + c * 64 + sr6) * (size_t)K + sgr;

  f32x4 acc[8][4] = {};
  s16x8 bfr[4][2];

  const int swz0 = ((0 + fkg) ^ (fr & 7)) * 16;
  const int swz1 = ((4 + fkg) ^ (fr & 7)) * 16;

  const int aRowBase = wm * 32 + fr;
  const int bRowBase = wn * 64 + fr;

  // ---- prologue: t0 {A0,A1,A2,B0..B3,A3}, t1 {A0,A1,A2,B0..B3} ----
  {
    char* a0 = (char*)&As[0][0] + wv * 1024;
    char* b0 = (char*)&Bs[0][0] + wv * 1024;
    async16(a0 + 0 * 8192, pAq[0]); async16(a0 + 1 * 8192, pAq[1]); async16(a0 + 2 * 8192, pAq[2]);
    async16(b0 + 0 * 8192, pBc[0]); async16(b0 + 1 * 8192, pBc[1]);
    async16(b0 + 2 * 8192, pBc[2]); async16(b0 + 3 * 8192, pBc[3]);
    async16(a0 + 3 * 8192, pAq[3]);
    char* a1 = (char*)&As[1][0] + wv * 1024;
    char* b1 = (char*)&Bs[1][0] + wv * 1024;
    async16(a1 + 0 * 8192, pAq[0] + 64); async16(a1 + 1 * 8192, pAq[1] + 64); async16(a1 + 2 * 8192, pAq[2] + 64);
    async16(b1 + 0 * 8192, pBc[0] + 64); async16(b1 + 1 * 8192, pBc[1] + 64);
    async16(b1 + 2 * 8192, pBc[2] + 64); async16(b1 + 3 * 8192, pBc[3] + 64);
  }

  const int NT = K >> 6;   // requires K >= 128

  for (int t = 0; t < NT; ++t) {
    const int p = t & 1;
    const char* Ab = (const char*)&As[p][0];
    const char* Bb = (const char*)&Bs[p][0];
    char* sA = (char*)&As[p][0] + wv * 1024;
    char* sB = (char*)&Bs[p][0] + wv * 1024;
    char* sAo = (char*)&As[p ^ 1][0] + wv * 1024;
    const int k1 = (t + 1 < NT ? t + 1 : 0) << 6;
    const int k2 = (t + 2 < NT ? t + 2 : 0) << 6;

    // ---------------- phase 0 ----------------
    asm volatile("s_waitcnt vmcnt(8)" ::: "memory");
    __builtin_amdgcn_sched_barrier(0);
    __builtin_amdgcn_s_barrier();
    __builtin_amdgcn_sched_barrier(0);
    {
#pragma unroll
      for (int nf = 0; nf < 4; ++nf) {
        const char* rb = Bb + (bRowBase + nf * 16) * 128;
        bfr[nf][0] = *(const s16x8*)(rb + swz0);
        bfr[nf][1] = *(const s16x8*)(rb + swz1);
      }
      s16x8 a_[2][2];
#pragma unroll
      for (int j = 0; j < 2; ++j) {
        const char* rb = Ab + (0 * 64 + aRowBase + j * 16) * 128;
        a_[j][0] = *(const s16x8*)(rb + swz0);
        a_[j][1] = *(const s16x8*)(rb + swz1);
      }
      async16(sAo + 3 * 8192, pAq[3] + k1);
      __builtin_amdgcn_s_setprio(1);
#pragma unroll
      for (int j = 0; j < 2; ++j)
#pragma unroll
        for (int kk = 0; kk < 2; ++kk)
#pragma unroll
          for (int nf = 0; nf < 4; ++nf)
            acc[j][nf] = mfma_bf16(a_[j][kk], bfr[nf][kk], acc[j][nf]);
      __builtin_amdgcn_s_setprio(0);
    }

    // ---------------- phase 1 ----------------
    __builtin_amdgcn_sched_barrier(0);
    __builtin_amdgcn_s_barrier();
    __builtin_amdgcn_sched_barrier(0);
    {
      s16x8 a_[2][2];
#pragma unroll
      for (int j = 0; j < 2; ++j) {
        const char* rb = Ab + (1 * 64 + aRowBase + j * 16) * 128;
        a_[j][0] = *(const s16x8*)(rb + swz0);
        a_[j][1] = *(const s16x8*)(rb + swz1);
      }
      async16(sA + 0 * 8192, pAq[0] + k2);
      async16(sB + 0 * 8192, pBc[0] + k2);
      __builtin_amdgcn_s_setprio(1);
#pragma unroll
      for (int j = 0; j < 2; ++j)
#pragma unroll
        for (int kk = 0; kk < 2; ++kk)
#pragma unroll
          for (int nf = 0; nf < 4; ++nf)
            acc[2 + j][nf] = mfma_bf16(a_[j][kk], bfr[nf][kk], acc[2 + j][nf]);
      __builtin_amdgcn_s_setprio(0);
    }

    // ---------------- phase 2 ----------------
    __builtin_amdgcn_sched_barrier(0);
    __builtin_amdgcn_s_barrier();
    __builtin_amdgcn_sched_barrier(0);
    {
      s16x8 a_[2][2];
#pragma unroll
      for (int j = 0; j < 2; ++j) {
        const char* rb = Ab + (2 * 64 + aRowBase + j * 16) * 128;
        a_[j][0] = *(const s16x8*)(rb + swz0);
        a_[j][1] = *(const s16x8*)(rb + swz1);
      }
      async16(sA + 1 * 8192, pAq[1] + k2);
      async16(sB + 1 * 8192, pBc[1] + k2);
      __builtin_amdgcn_s_setprio(1);
#pragma unroll
      for (int j = 0; j < 2; ++j)
#pragma unroll
        for (int kk = 0; kk < 2; ++kk)
#pragma unroll
          for (int nf = 0; nf < 4; ++nf)
            acc[4 + j][nf] = mfma_bf16(a_[j][kk], bfr[nf][kk], acc[4 + j][nf]);
      __builtin_amdgcn_s_setprio(0);
    }

    // ---------------- phase 3 ----------------
    asm volatile("s_waitcnt vmcnt(12)" ::: "memory");
    __builtin_amdgcn_sched_barrier(0);
    __builtin_amdgcn_s_barrier();
    __builtin_amdgcn_sched_barrier(0);
    {
      s16x8 a_[2][2];
#pragma unroll
      for (int j = 0; j < 2; ++j) {
        const char* rb = Ab + (3 * 64 + aRowBase + j * 16) * 128;
        a_[j][0] = *(const s16x8*)(rb + swz0);
        a_[j][1] = *(const s16x8*)(rb + swz1);
      }
      async16(sA + 2 * 8192, pAq[2] + k2);
      async16(sB + 2 * 8192, pBc[2] + k2);
      async16(sB + 3 * 8192, pBc[3] + k2);
      __builtin_amdgcn_s_setprio(1);
#pragma unroll
      for (int j = 0; j < 2; ++j)
#pragma unroll
        for (int kk = 0; kk < 2; ++kk)
#pragma unroll
          for (int nf = 0; nf < 4; ++nf)
            acc[6 + j][nf] = mfma_bf16(a_[j][kk], bfr[nf][kk], acc[6 + j][nf]);
      __builtin_amdgcn_s_setprio(0);
    }
  }

  asm volatile("s_waitcnt vmcnt(0)" ::: "memory");  // drain clamped tail stages

  // epilogue: C/D layout col=lane&15, row=(lane>>4)*4+i (m89-verified)
#pragma unroll
  for (int nf = 0; nf < 4; ++nf) {
    const long col = bcol + wn * 64 + nf * 16 + fr;
    const float bv = bias[col];
#pragma unroll
    for (int mf = 0; mf < 8; ++mf) {
      const long row0 = brow + wm * 128 + mf * 16 + fkg * 4;
#pragma unroll
      for (int i = 0; i < 4; ++i) {
        float v = fmaxf(acc[mf][nf][i] + bv, 0.0f);
        C[(row0 + i) * (long)N + col] = f2bf(v);
      }
    }
  }
}

// ---------------- 128x128 GEMM (layer 3: N=1000->1024) ----------------
template <int RELU, int CBF16>
__global__ __launch_bounds__(256) void gemm_bt(
    const u16* __restrict__ A, const u16* __restrict__ B,
    const float* __restrict__ bias, void* __restrict__ Cv,
    int Ntrue, int K) {
  __shared__ __align__(16) u16 As[128 * 32];
  __shared__ __align__(16) u16 Bs[128 * 32];
  const int tid = threadIdx.x;
  const int lane = tid & 63;
  const int wv = tid >> 6;
  const long brow = (long)blockIdx.y * 128;
  const long bcol = (long)blockIdx.x * 128;
  const int wm = (wv >> 1) * 64;
  const int wn = (wv & 1) * 64;

  const u16* gA0 = A + (brow + (tid >> 2)) * (long)K + (tid & 3) * 8;
  const u16* gA1 = gA0 + (size_t)64 * K;
  const u16* gB0 = B + (bcol + (tid >> 2)) * (long)K + (tid & 3) * 8;
  const u16* gB1 = gB0 + (size_t)64 * K;
  char* lA0 = (char*)As + wv * 1024;
  char* lA1 = (char*)As + 4096 + wv * 1024;
  char* lB0 = (char*)Bs + wv * 1024;
  char* lB1 = (char*)Bs + 4096 + wv * 1024;

  f32x4 acc[4][4] = {};
  const int fr = lane & 15;
  const int fk = (lane >> 4) * 8;

  for (int kt = 0; kt < K; kt += 32) {
    async16(lA0, gA0 + kt);
    async16(lA1, gA1 + kt);
    async16(lB0, gB0 + kt);
    async16(lB1, gB1 + kt);
    __syncthreads();
    s16x8 a[4], b[4];
#pragma unroll
    for (int m = 0; m < 4; ++m) a[m] = *(const s16x8*)&As[(wm + m * 16 + fr) * 32 + fk];
#pragma unroll
    for (int n = 0; n < 4; ++n) b[n] = *(const s16x8*)&Bs[(wn + n * 16 + fr) * 32 + fk];
#pragma unroll
    for (int m = 0; m < 4; ++m)
#pragma unroll
      for (int n = 0; n < 4; ++n)
        acc[m][n] = mfma_bf16(a[m], b[n], acc[m][n]);
    __syncthreads();
  }

  const long col0 = bcol + wn + fr;
  const long row0 = brow + wm + ((lane >> 4) << 2);
#pragma unroll
  for (int n = 0; n < 4; ++n) {
    long col = col0 + n * 16;
    if (!CBF16 && col >= Ntrue) continue;
    float bv = bias[col];
#pragma unroll
    for (int m = 0; m < 4; ++m) {
#pragma unroll
      for (int i = 0; i < 4; ++i) {
        float v = acc[m][n][i] + bv;
        if (RELU) v = fmaxf(v, 0.0f);
        long off = (row0 + m * 16 + i) * (long)Ntrue + col;
        if (CBF16) ((u16*)Cv)[off] = f2bf(v);
        else ((float*)Cv)[off] = v;
      }
    }
  }
}

// ---------------- launch ----------------
extern "C" void kernel_launch(void* const* d_in, const int* in_sizes, int n_in,
                              void* d_out, int out_size, void* d_ws, size_t ws_size,
                              hipStream_t stream) {
  const float* x  = (const float*)d_in[0];
  const float* w1 = (const float*)d_in[1];
  const float* s1 = (const float*)d_in[2];
  const float* b1 = (const float*)d_in[3];
  const float* w2 = (const float*)d_in[4];
  const float* s2 = (const float*)d_in[5];
  const float* b2 = (const float*)d_in[6];
  const float* w3 = (const float*)d_in[7];
  const float* s3 = (const float*)d_in[8];
  const float* b3 = (const float*)d_in[9];
  float* out = (float*)d_out;

  const int n1 = 4096 * 2048, n2 = 4096 * 4096, n3 = 1000 * 4096;

  char* ws = (char*)d_ws;
  u32*   meta = (u32*)ws;                  // 3 x 8 u32
  uint2* cand = (uint2*)(ws + 0x10000);    // 3 x 65536 x 8B, ends 0x190000
  u16* Wb = (u16*)(ws + (2l  << 20));      // 32 MiB, reused per layer
  u16* H1 = (u16*)(ws + (34l << 20));      // 32 MiB (gemm1 output)
  u32* gh20 = (u32*)(ws + (34l << 20));    // 12 MiB, aliases H1 (dead before gemm1)
  u16* H2 = (u16*)(ws + (66l << 20));      // 32 MiB
  u16* Xb = (u16*)(ws + (66l << 20));      // 16 MiB, aliases H2 (dead before gemm2 writes H2)

  // selection: one 20-bit hist pass (+ fused x->bf16) + one select dispatch
  hipMemsetAsync(ws, 0, 0x1000, stream);                           // meta
  hipMemsetAsync(gh20, 0, (size_t)12 << 20, stream);               // 3 x 1M bins
  hist20_k<<<1024, 256, 0, stream>>>((const float4*)x, (ushort4*)Xb, n1 / 4,
                                     (const uint4*)s1, n1 / 4, (const uint4*)s2, n2 / 4,
                                     (const uint4*)s3, n3 / 4, gh20);
  select20_k<<<3, 1024, 0, stream>>>(gh20, meta, (u32)(n1 / 2), (u32)(n2 / 2), (u32)(n3 / 2));

  // Layer 1: (4096x2048) -> 4096, relu, bf16
  build_k<<<512, 256, 0, stream>>>((const float4*)w1, (const uint4*)s1, (ushort4*)Wb,
                                   n1 / 4, n1 / 4, meta + 0, cand + 0);
  finalize_k<<<1, 1024, 0, stream>>>(Wb, w1, meta + 0, cand + 0);
  gemm256<<<dim3(16, 16), 512, 0, stream>>>(Xb, Wb, b1, H1, 4096, 2048);

  // Layer 2: 4096 -> 4096, relu, bf16
  build_k<<<512, 256, 0, stream>>>((const float4*)w2, (const uint4*)s2, (ushort4*)Wb,
                                   n2 / 4, n2 / 4, meta + 8, cand + CANDCAP);
  finalize_k<<<1, 1024, 0, stream>>>(Wb, w2, meta + 8, cand + CANDCAP);
  gemm256<<<dim3(16, 16), 512, 0, stream>>>(H1, Wb, b2, H2, 4096, 4096);

  // Layer 3: 4096 -> 1000 (rows padded to 1024 inside build_k), fp32 out
  build_k<<<512, 256, 0, stream>>>((const float4*)w3, (const uint4*)s3, (ushort4*)Wb,
                                   n3 / 4, (1024 * 4096) / 4, meta + 16, cand + 2 * CANDCAP);
  finalize_k<<<1, 1024, 0, stream>>>(Wb, w3, meta + 16, cand + 2 * CANDCAP);
  gemm_bt<0, 0><<<dim3(8, 32), 256, 0, stream>>>(H2, Wb, b3, out, 1000, 4096);
}

// Round 8
// 454.741 us; speedup vs baseline: 4.4499x; 4.4499x over previous
//
#include <hip/hip_runtime.h>

typedef unsigned int u32;
typedef unsigned short u16;
typedef short s16x8 __attribute__((ext_vector_type(8)));
typedef __bf16 bf16x8 __attribute__((ext_vector_type(8)));
typedef float f32x4 __attribute__((ext_vector_type(4)));

#define KEYMASK 0x7fffffffu
#define NB1 1024
#define NB2 4096
#define CANDCAP 65536
#define TIECAP 2048

__device__ __forceinline__ u16 f2bf(float f) {
  u32 u = __builtin_bit_cast(u32, f);
  return (u16)((u + 0x7fffu + ((u >> 16) & 1u)) >> 16);
}

// Handles either builtin signature (short8 or __bf16x8) across ROCm versions.
struct ABFrag {
  s16x8 v;
  __device__ operator s16x8() const { return v; }
  __device__ operator bf16x8() const { return __builtin_bit_cast(bf16x8, v); }
};

__device__ __forceinline__ f32x4 mfma_bf16(s16x8 a, s16x8 b, f32x4 c) {
  return __builtin_amdgcn_mfma_f32_16x16x32_bf16(ABFrag{a}, ABFrag{b}, c, 0, 0, 0);
}

__device__ __forceinline__ void async16(void* lds, const void* g) {
  __builtin_amdgcn_global_load_lds(
      (__attribute__((address_space(1))) void*)(const_cast<void*>(g)),
      (__attribute__((address_space(3))) void*)lds, 16, 0, 0);
}

// ================= fused 3-layer radix selection (LDS histograms) =================
// meta per layer (8 u32): [0]=selA(10b) [1]=r1 [2]=selB(12b) [3]=r2 [4]=candCount
// NOTE (R7 lesson): never histogram via scattered GLOBAL atomics on gfx950 —
// they write through to HBM (~1 GB traffic, 10x slowdown). LDS bins only.

// Pass 1 (+ fused x->bf16 convert): 10-bit prefix histogram, 4-way replicated bins.
__global__ void hist1_k(const float4* __restrict__ x, ushort4* __restrict__ xb, int xn4,
                        const uint4* __restrict__ sa, int na,
                        const uint4* __restrict__ sb, int nb,
                        const uint4* __restrict__ sc, int nc,
                        u32* __restrict__ gh) {
  __shared__ u32 h[3 * NB1 * 4];  // 48KB: [l][bin][replica]
  for (int i = threadIdx.x; i < 3 * NB1 * 4; i += blockDim.x) h[i] = 0;
  __syncthreads();
  int stride = gridDim.x * blockDim.x;
  // fused convert (independent streaming work)
  for (int i = blockIdx.x * blockDim.x + threadIdx.x; i < xn4; i += stride) {
    float4 v = x[i];
    ushort4 o;
    o.x = f2bf(v.x); o.y = f2bf(v.y); o.z = f2bf(v.z); o.w = f2bf(v.w);
    xb[i] = o;
  }
  const int rep = threadIdx.x & 3;
  const uint4* sp[3] = {sa, sb, sc};
  int nn[3] = {na, nb, nc};
  for (int l = 0; l < 3; ++l) {
    const uint4* s = sp[l];
    int n4 = nn[l];
    u32* hl = &h[l * NB1 * 4 + rep];
    for (int i = blockIdx.x * blockDim.x + threadIdx.x; i < n4; i += stride) {
      uint4 v = s[i];
      atomicAdd(&hl[((v.x & KEYMASK) >> 21) * 4], 1u);
      atomicAdd(&hl[((v.y & KEYMASK) >> 21) * 4], 1u);
      atomicAdd(&hl[((v.z & KEYMASK) >> 21) * 4], 1u);
      atomicAdd(&hl[((v.w & KEYMASK) >> 21) * 4], 1u);
    }
  }
  __syncthreads();
  for (int i = threadIdx.x; i < 3 * NB1; i += blockDim.x) {
    u32 c = h[i * 4] + h[i * 4 + 1] + h[i * 4 + 2] + h[i * 4 + 3];
    if (c) atomicAdd(&gh[i], c);
  }
}

// Pass 2: 12-bit sub-histogram (bits 20..9) of elements whose 10-bit prefix == selA.
__global__ void hist2_k(const uint4* __restrict__ sa, int na,
                        const uint4* __restrict__ sb, int nb,
                        const uint4* __restrict__ sc, int nc,
                        u32* __restrict__ gh, const u32* __restrict__ meta) {
  __shared__ u32 h[3 * NB2];  // 48KB
  for (int i = threadIdx.x; i < 3 * NB2; i += blockDim.x) h[i] = 0;
  __syncthreads();
  const uint4* sp[3] = {sa, sb, sc};
  int nn[3] = {na, nb, nc};
  int stride = gridDim.x * blockDim.x;
  for (int l = 0; l < 3; ++l) {
    const uint4* s = sp[l];
    int n4 = nn[l];
    u32 selA = meta[l * 8 + 0];
    u32* hl = &h[l * NB2];
    for (int i = blockIdx.x * blockDim.x + threadIdx.x; i < n4; i += stride) {
      uint4 v = s[i];
      u32 k;
      k = v.x & KEYMASK; if ((k >> 21) == selA) atomicAdd(&hl[(k >> 9) & 0xfffu], 1u);
      k = v.y & KEYMASK; if ((k >> 21) == selA) atomicAdd(&hl[(k >> 9) & 0xfffu], 1u);
      k = v.z & KEYMASK; if ((k >> 21) == selA) atomicAdd(&hl[(k >> 9) & 0xfffu], 1u);
      k = v.w & KEYMASK; if ((k >> 21) == selA) atomicAdd(&hl[(k >> 9) & 0xfffu], 1u);
    }
  }
  __syncthreads();
  for (int i = threadIdx.x; i < 3 * NB2; i += blockDim.x) {
    u32 c = h[i];
    if (c) atomicAdd(&gh[i], c);
  }
}

template <int STAGE>
__global__ void select_k(const u32* __restrict__ hist, u32* __restrict__ meta,
                         u32 r0, u32 r1, u32 r2) {
  const int l = blockIdx.x;
  const int nbins = (STAGE == 1) ? NB1 : NB2;
  const u32* hl = hist + l * nbins;
  __shared__ u32 part[256];
  int tid = threadIdx.x;
  int chunk = nbins >> 8;
  u32 sm = 0;
  for (int i = tid * chunk; i < (tid + 1) * chunk; ++i) sm += hl[i];
  part[tid] = sm;
  __syncthreads();
  if (tid == 0) {
    u32 r = (STAGE == 1) ? (l == 0 ? r0 : (l == 1 ? r1 : r2)) : meta[l * 8 + 1];
    u32 c = 0; int t = 0;
    for (; t < 256; ++t) { if (c + part[t] > r) break; c += part[t]; }
    u32 rr = r - c;
    int bin = t * chunk;
    for (;;) { u32 hv = hl[bin]; if (rr < hv) break; rr -= hv; ++bin; }
    if (STAGE == 1) { meta[l * 8 + 0] = (u32)bin; meta[l * 8 + 1] = rr; }
    else           { meta[l * 8 + 2] = (u32)bin; meta[l * 8 + 3] = rr; }
  }
}

// Fused mask+cast build: 22-bit prefix > t22 -> bf16(w); < -> 0; == -> 0 + candidate.
// i in [n4, n4pad): write zeros (pad rows for the N=1000->1024 GEMM).
__global__ void build_k(const float4* __restrict__ w, const uint4* __restrict__ s,
                        ushort4* __restrict__ wb, int n4, int n4pad,
                        u32* __restrict__ meta, uint2* __restrict__ cand) {
  u32 t22 = (meta[0] << 12) | meta[2];
  int stride = gridDim.x * blockDim.x;
  for (int i = blockIdx.x * blockDim.x + threadIdx.x; i < n4pad; i += stride) {
    if (i >= n4) { wb[i] = make_ushort4(0, 0, 0, 0); continue; }
    uint4 sv = s[i];
    float4 wv = w[i];
    u32 k0 = sv.x & KEYMASK, k1 = sv.y & KEYMASK, k2 = sv.z & KEYMASK, k3 = sv.w & KEYMASK;
    ushort4 o;
    o.x = ((k0 >> 9) > t22) ? f2bf(wv.x) : (u16)0;
    o.y = ((k1 >> 9) > t22) ? f2bf(wv.y) : (u16)0;
    o.z = ((k2 >> 9) > t22) ? f2bf(wv.z) : (u16)0;
    o.w = ((k3 >> 9) > t22) ? f2bf(wv.w) : (u16)0;
    wb[i] = o;
    u32 base = (u32)i * 4u;
    if ((k0 >> 9) == t22) { u32 p = atomicAdd(&meta[4], 1u); if (p < CANDCAP) cand[p] = make_uint2(k0, base); }
    if ((k1 >> 9) == t22) { u32 p = atomicAdd(&meta[4], 1u); if (p < CANDCAP) cand[p] = make_uint2(k1, base + 1u); }
    if ((k2 >> 9) == t22) { u32 p = atomicAdd(&meta[4], 1u); if (p < CANDCAP) cand[p] = make_uint2(k2, base + 2u); }
    if ((k3 >> 9) == t22) { u32 p = atomicAdd(&meta[4], 1u); if (p < CANDCAP) cand[p] = make_uint2(k3, base + 3u); }
  }
}

// Exact low-9-bit select among candidates + stable-argsort tie semantics.
__global__ void finalize_k(u16* __restrict__ wb, const float* __restrict__ w,
                           const u32* __restrict__ meta, const uint2* __restrict__ cand) {
  __shared__ u32 h[512];
  __shared__ u32 tie[TIECAP];
  __shared__ u32 tcnt, t9s, qs;
  int tid = threadIdx.x;
  for (int i = tid; i < 512; i += blockDim.x) h[i] = 0;
  if (tid == 0) tcnt = 0;
  __syncthreads();
  u32 m = meta[4]; if (m > CANDCAP) m = CANDCAP;
  for (u32 i = tid; i < m; i += blockDim.x) atomicAdd(&h[cand[i].x & 0x1ffu], 1u);
  __syncthreads();
  if (tid == 0) {
    u32 r = meta[3];
    u32 c = 0; int bin = 0;
    for (;;) { u32 hv = h[bin]; if (c + hv > r) break; c += hv; ++bin; }
    t9s = (u32)bin; qs = r - c;
  }
  __syncthreads();
  u32 t9 = t9s, q = qs;
  for (u32 i = tid; i < m; i += blockDim.x) {
    uint2 cd = cand[i];
    u32 k9 = cd.x & 0x1ffu;
    if (k9 > t9) wb[cd.y] = f2bf(w[cd.y]);
    else if (k9 == t9) { u32 p = atomicAdd(&tcnt, 1u); if (p < TIECAP) tie[p] = cd.y; }
  }
  __syncthreads();
  u32 tc = tcnt; if (tc > TIECAP) tc = TIECAP;
  for (u32 i = tid; i < tc; i += blockDim.x) {
    u32 my = tie[i];
    u32 rk = 0;
    for (u32 j = 0; j < tc; ++j) rk += (tie[j] < my) ? 1u : 0u;
    if (rk >= q) wb[my] = f2bf(w[my]);
  }
}

// ======== 256x256 GEMM, BK=64, 8 waves, 4-phase counted-vmcnt pipeline ========
// R4 schedule (best measured: 128.6us / 45% MfmaUtil on 4096^3).
// A LDS: chunk q = LDS rows q*64.., global rows half*128+q*32+r. B: 4 col chunks.
// XOR-swizzle per 16B granule (g^(R&7)); linear LDS dest + inverse-swizzled src.
// Stage: ph0: A3(t+1)->p^1 | ph1: A0,B0(t+2) | ph2: A1,B1 | ph3: A2,B2,B3.
// Waits: vmcnt(8)@ph0 (tile t minus A3 landed), vmcnt(12)@ph3 (A3(t) landed).
__global__ __launch_bounds__(512) void gemm256(
    const u16* __restrict__ A, const u16* __restrict__ B,
    const float* __restrict__ bias, u16* __restrict__ C,
    int N, int K) {
  __shared__ __align__(16) u16 As[2][256 * 64];
  __shared__ __align__(16) u16 Bs[2][256 * 64];
  const int tid = threadIdx.x;
  const int lane = tid & 63;
  const int wv = tid >> 6;
  const int wm = wv >> 2;        // 0..1
  const int wn = wv & 3;         // 0..3
  const int fr = lane & 15;
  const int fkg = lane >> 4;     // 0..3
  const long brow = (long)blockIdx.y * 256;
  const long bcol = (long)blockIdx.x * 256;

  const int sr6 = tid >> 3;                       // 0..63
  const int sgr = ((tid & 7) ^ (sr6 & 7)) << 3;   // inverse-swizzled src elem offset
  const int ha = tid >> 8;                        // A half (0/1)
  const int ra = sr6 & 31;                        // A row within quarter
  const u16* pAq[4];
  const u16* pBc[4];
#pragma unroll
  for (int q = 0; q < 4; ++q)
    pAq[q] = A + (size_t)(brow + ha * 128 + q * 32 + ra) * (size_t)K + sgr;
#pragma unroll
  for (int c = 0; c < 4; ++c)
    pBc[c] = B + (size_t)(bcol + c * 64 + sr6) * (size_t)K + sgr;

  f32x4 acc[8][4] = {};
  s16x8 bfr[4][2];

  const int swz0 = ((0 + fkg) ^ (fr & 7)) * 16;
  const int swz1 = ((4 + fkg) ^ (fr & 7)) * 16;

  const int aRowBase = wm * 32 + fr;
  const int bRowBase = wn * 64 + fr;

  // ---- prologue: t0 {A0,A1,A2,B0..B3,A3}, t1 {A0,A1,A2,B0..B3} ----
  {
    char* a0 = (char*)&As[0][0] + wv * 1024;
    char* b0 = (char*)&Bs[0][0] + wv * 1024;
    async16(a0 + 0 * 8192, pAq[0]); async16(a0 + 1 * 8192, pAq[1]); async16(a0 + 2 * 8192, pAq[2]);
    async16(b0 + 0 * 8192, pBc[0]); async16(b0 + 1 * 8192, pBc[1]);
    async16(b0 + 2 * 8192, pBc[2]); async16(b0 + 3 * 8192, pBc[3]);
    async16(a0 + 3 * 8192, pAq[3]);
    char* a1 = (char*)&As[1][0] + wv * 1024;
    char* b1 = (char*)&Bs[1][0] + wv * 1024;
    async16(a1 + 0 * 8192, pAq[0] + 64); async16(a1 + 1 * 8192, pAq[1] + 64); async16(a1 + 2 * 8192, pAq[2] + 64);
    async16(b1 + 0 * 8192, pBc[0] + 64); async16(b1 + 1 * 8192, pBc[1] + 64);
    async16(b1 + 2 * 8192, pBc[2] + 64); async16(b1 + 3 * 8192, pBc[3] + 64);
  }

  const int NT = K >> 6;   // requires K >= 128

  for (int t = 0; t < NT; ++t) {
    const int p = t & 1;
    const char* Ab = (const char*)&As[p][0];
    const char* Bb = (const char*)&Bs[p][0];
    char* sA = (char*)&As[p][0] + wv * 1024;
    char* sB = (char*)&Bs[p][0] + wv * 1024;
    char* sAo = (char*)&As[p ^ 1][0] + wv * 1024;
    const int k1 = (t + 1 < NT ? t + 1 : 0) << 6;
    const int k2 = (t + 2 < NT ? t + 2 : 0) << 6;

    // ---------------- phase 0 ----------------
    asm volatile("s_waitcnt vmcnt(8)" ::: "memory");
    __builtin_amdgcn_sched_barrier(0);
    __builtin_amdgcn_s_barrier();
    __builtin_amdgcn_sched_barrier(0);
    {
#pragma unroll
      for (int nf = 0; nf < 4; ++nf) {
        const char* rb = Bb + (bRowBase + nf * 16) * 128;
        bfr[nf][0] = *(const s16x8*)(rb + swz0);
        bfr[nf][1] = *(const s16x8*)(rb + swz1);
      }
      s16x8 a_[2][2];
#pragma unroll
      for (int j = 0; j < 2; ++j) {
        const char* rb = Ab + (0 * 64 + aRowBase + j * 16) * 128;
        a_[j][0] = *(const s16x8*)(rb + swz0);
        a_[j][1] = *(const s16x8*)(rb + swz1);
      }
      async16(sAo + 3 * 8192, pAq[3] + k1);
      __builtin_amdgcn_s_setprio(1);
#pragma unroll
      for (int j = 0; j < 2; ++j)
#pragma unroll
        for (int kk = 0; kk < 2; ++kk)
#pragma unroll
          for (int nf = 0; nf < 4; ++nf)
            acc[j][nf] = mfma_bf16(a_[j][kk], bfr[nf][kk], acc[j][nf]);
      __builtin_amdgcn_s_setprio(0);
    }

    // ---------------- phase 1 ----------------
    __builtin_amdgcn_sched_barrier(0);
    __builtin_amdgcn_s_barrier();
    __builtin_amdgcn_sched_barrier(0);
    {
      s16x8 a_[2][2];
#pragma unroll
      for (int j = 0; j < 2; ++j) {
        const char* rb = Ab + (1 * 64 + aRowBase + j * 16) * 128;
        a_[j][0] = *(const s16x8*)(rb + swz0);
        a_[j][1] = *(const s16x8*)(rb + swz1);
      }
      async16(sA + 0 * 8192, pAq[0] + k2);
      async16(sB + 0 * 8192, pBc[0] + k2);
      __builtin_amdgcn_s_setprio(1);
#pragma unroll
      for (int j = 0; j < 2; ++j)
#pragma unroll
        for (int kk = 0; kk < 2; ++kk)
#pragma unroll
          for (int nf = 0; nf < 4; ++nf)
            acc[2 + j][nf] = mfma_bf16(a_[j][kk], bfr[nf][kk], acc[2 + j][nf]);
      __builtin_amdgcn_s_setprio(0);
    }

    // ---------------- phase 2 ----------------
    __builtin_amdgcn_sched_barrier(0);
    __builtin_amdgcn_s_barrier();
    __builtin_amdgcn_sched_barrier(0);
    {
      s16x8 a_[2][2];
#pragma unroll
      for (int j = 0; j < 2; ++j) {
        const char* rb = Ab + (2 * 64 + aRowBase + j * 16) * 128;
        a_[j][0] = *(const s16x8*)(rb + swz0);
        a_[j][1] = *(const s16x8*)(rb + swz1);
      }
      async16(sA + 1 * 8192, pAq[1] + k2);
      async16(sB + 1 * 8192, pBc[1] + k2);
      __builtin_amdgcn_s_setprio(1);
#pragma unroll
      for (int j = 0; j < 2; ++j)
#pragma unroll
        for (int kk = 0; kk < 2; ++kk)
#pragma unroll
          for (int nf = 0; nf < 4; ++nf)
            acc[4 + j][nf] = mfma_bf16(a_[j][kk], bfr[nf][kk], acc[4 + j][nf]);
      __builtin_amdgcn_s_setprio(0);
    }

    // ---------------- phase 3 ----------------
    asm volatile("s_waitcnt vmcnt(12)" ::: "memory");
    __builtin_amdgcn_sched_barrier(0);
    __builtin_amdgcn_s_barrier();
    __builtin_amdgcn_sched_barrier(0);
    {
      s16x8 a_[2][2];
#pragma unroll
      for (int j = 0; j < 2; ++j) {
        const char* rb = Ab + (3 * 64 + aRowBase + j * 16) * 128;
        a_[j][0] = *(const s16x8*)(rb + swz0);
        a_[j][1] = *(const s16x8*)(rb + swz1);
      }
      async16(sA + 2 * 8192, pAq[2] + k2);
      async16(sB + 2 * 8192, pBc[2] + k2);
      async16(sB + 3 * 8192, pBc[3] + k2);
      __builtin_amdgcn_s_setprio(1);
#pragma unroll
      for (int j = 0; j < 2; ++j)
#pragma unroll
        for (int kk = 0; kk < 2; ++kk)
#pragma unroll
          for (int nf = 0; nf < 4; ++nf)
            acc[6 + j][nf] = mfma_bf16(a_[j][kk], bfr[nf][kk], acc[6 + j][nf]);
      __builtin_amdgcn_s_setprio(0);
    }
  }

  asm volatile("s_waitcnt vmcnt(0)" ::: "memory");  // drain clamped tail stages

  // epilogue: C/D layout col=lane&15, row=(lane>>4)*4+i (m89-verified)
#pragma unroll
  for (int nf = 0; nf < 4; ++nf) {
    const long col = bcol + wn * 64 + nf * 16 + fr;
    const float bv = bias[col];
#pragma unroll
    for (int mf = 0; mf < 8; ++mf) {
      const long row0 = brow + wm * 128 + mf * 16 + fkg * 4;
#pragma unroll
      for (int i = 0; i < 4; ++i) {
        float v = fmaxf(acc[mf][nf][i] + bv, 0.0f);
        C[(row0 + i) * (long)N + col] = f2bf(v);
      }
    }
  }
}

// ---------------- 128x128 GEMM (layer 3: N=1000->1024) ----------------
template <int RELU, int CBF16>
__global__ __launch_bounds__(256) void gemm_bt(
    const u16* __restrict__ A, const u16* __restrict__ B,
    const float* __restrict__ bias, void* __restrict__ Cv,
    int Ntrue, int K) {
  __shared__ __align__(16) u16 As[128 * 32];
  __shared__ __align__(16) u16 Bs[128 * 32];
  const int tid = threadIdx.x;
  const int lane = tid & 63;
  const int wv = tid >> 6;
  const long brow = (long)blockIdx.y * 128;
  const long bcol = (long)blockIdx.x * 128;
  const int wm = (wv >> 1) * 64;
  const int wn = (wv & 1) * 64;

  const u16* gA0 = A + (brow + (tid >> 2)) * (long)K + (tid & 3) * 8;
  const u16* gA1 = gA0 + (size_t)64 * K;
  const u16* gB0 = B + (bcol + (tid >> 2)) * (long)K + (tid & 3) * 8;
  const u16* gB1 = gB0 + (size_t)64 * K;
  char* lA0 = (char*)As + wv * 1024;
  char* lA1 = (char*)As + 4096 + wv * 1024;
  char* lB0 = (char*)Bs + wv * 1024;
  char* lB1 = (char*)Bs + 4096 + wv * 1024;

  f32x4 acc[4][4] = {};
  const int fr = lane & 15;
  const int fk = (lane >> 4) * 8;

  for (int kt = 0; kt < K; kt += 32) {
    async16(lA0, gA0 + kt);
    async16(lA1, gA1 + kt);
    async16(lB0, gB0 + kt);
    async16(lB1, gB1 + kt);
    __syncthreads();
    s16x8 a[4], b[4];
#pragma unroll
    for (int m = 0; m < 4; ++m) a[m] = *(const s16x8*)&As[(wm + m * 16 + fr) * 32 + fk];
#pragma unroll
    for (int n = 0; n < 4; ++n) b[n] = *(const s16x8*)&Bs[(wn + n * 16 + fr) * 32 + fk];
#pragma unroll
    for (int m = 0; m < 4; ++m)
#pragma unroll
      for (int n = 0; n < 4; ++n)
        acc[m][n] = mfma_bf16(a[m], b[n], acc[m][n]);
    __syncthreads();
  }

  const long col0 = bcol + wn + fr;
  const long row0 = brow + wm + ((lane >> 4) << 2);
#pragma unroll
  for (int n = 0; n < 4; ++n) {
    long col = col0 + n * 16;
    if (!CBF16 && col >= Ntrue) continue;
    float bv = bias[col];
#pragma unroll
    for (int m = 0; m < 4; ++m) {
#pragma unroll
      for (int i = 0; i < 4; ++i) {
        float v = acc[m][n][i] + bv;
        if (RELU) v = fmaxf(v, 0.0f);
        long off = (row0 + m * 16 + i) * (long)Ntrue + col;
        if (CBF16) ((u16*)Cv)[off] = f2bf(v);
        else ((float*)Cv)[off] = v;
      }
    }
  }
}

// ---------------- launch ----------------
extern "C" void kernel_launch(void* const* d_in, const int* in_sizes, int n_in,
                              void* d_out, int out_size, void* d_ws, size_t ws_size,
                              hipStream_t stream) {
  const float* x  = (const float*)d_in[0];
  const float* w1 = (const float*)d_in[1];
  const float* s1 = (const float*)d_in[2];
  const float* b1 = (const float*)d_in[3];
  const float* w2 = (const float*)d_in[4];
  const float* s2 = (const float*)d_in[5];
  const float* b2 = (const float*)d_in[6];
  const float* w3 = (const float*)d_in[7];
  const float* s3 = (const float*)d_in[8];
  const float* b3 = (const float*)d_in[9];
  float* out = (float*)d_out;

  const int n1 = 4096 * 2048, n2 = 4096 * 4096, n3 = 1000 * 4096;

  char* ws = (char*)d_ws;
  u32*   meta = (u32*)ws;                  // 3 x 8 u32
  u32*   gh1  = (u32*)(ws + 0x1000);       // 3 x 1024
  u32*   gh2  = (u32*)(ws + 0x4000);       // 3 x 4096, ends 0x10000
  uint2* cand = (uint2*)(ws + 0x10000);    // 3 x 65536 x 8B, ends 0x190000
  u16* Wb = (u16*)(ws + (2l  << 20));      // 32 MiB, reused per layer
  u16* H1 = (u16*)(ws + (34l << 20));      // 32 MiB
  u16* H2 = (u16*)(ws + (66l << 20));      // 32 MiB
  u16* Xb = (u16*)(ws + (66l << 20));      // 16 MiB, aliases H2 (dead before gemm2 writes H2)

  // fused selection: convert + hists + selects for all 3 layers
  hipMemsetAsync(ws, 0, 0x10000, stream);
  hist1_k<<<256, 1024, 0, stream>>>((const float4*)x, (ushort4*)Xb, n1 / 4,
                                    (const uint4*)s1, n1 / 4, (const uint4*)s2, n2 / 4,
                                    (const uint4*)s3, n3 / 4, gh1);
  select_k<1><<<3, 256, 0, stream>>>(gh1, meta, (u32)(n1 / 2), (u32)(n2 / 2), (u32)(n3 / 2));
  hist2_k<<<256, 1024, 0, stream>>>((const uint4*)s1, n1 / 4, (const uint4*)s2, n2 / 4,
                                    (const uint4*)s3, n3 / 4, gh2, meta);
  select_k<2><<<3, 256, 0, stream>>>(gh2, meta, 0, 0, 0);

  // Layer 1: (4096x2048) -> 4096, relu, bf16
  build_k<<<512, 256, 0, stream>>>((const float4*)w1, (const uint4*)s1, (ushort4*)Wb,
                                   n1 / 4, n1 / 4, meta + 0, cand + 0);
  finalize_k<<<1, 1024, 0, stream>>>(Wb, w1, meta + 0, cand + 0);
  gemm256<<<dim3(16, 16), 512, 0, stream>>>(Xb, Wb, b1, H1, 4096, 2048);

  // Layer 2: 4096 -> 4096, relu, bf16
  build_k<<<512, 256, 0, stream>>>((const float4*)w2, (const uint4*)s2, (ushort4*)Wb,
                                   n2 / 4, n2 / 4, meta + 8, cand + CANDCAP);
  finalize_k<<<1, 1024, 0, stream>>>(Wb, w2, meta + 8, cand + CANDCAP);
  gemm256<<<dim3(16, 16), 512, 0, stream>>>(H1, Wb, b2, H2, 4096, 4096);

  // Layer 3: 4096 -> 1000 (rows padded to 1024 inside build_k), fp32 out
  build_k<<<512, 256, 0, stream>>>((const float4*)w3, (const uint4*)s3, (ushort4*)Wb,
                                   n3 / 4, (1024 * 4096) / 4, meta + 16, cand + 2 * CANDCAP);
  finalize_k<<<1, 1024, 0, stream>>>(Wb, w3, meta + 16, cand + 2 * CANDCAP);
  gemm_bt<0, 0><<<dim3(8, 32), 256, 0, stream>>>(H2, Wb, b3, out, 1000, 4096);
}

// Round 9
// 446.857 us; speedup vs baseline: 4.5284x; 1.0176x over previous
//
#include <hip/hip_runtime.h>

typedef unsigned int u32;
typedef unsigned short u16;
typedef short s16x8 __attribute__((ext_vector_type(8)));
typedef __bf16 bf16x8 __attribute__((ext_vector_type(8)));
typedef float f32x4 __attribute__((ext_vector_type(4)));

#define KEYMASK 0x7fffffffu
#define NB1 1024
#define NB2 4096
#define CANDCAP 65536
#define TIECAP 2048

__device__ __forceinline__ u16 f2bf(float f) {
  u32 u = __builtin_bit_cast(u32, f);
  return (u16)((u + 0x7fffu + ((u >> 16) & 1u)) >> 16);
}

// Handles either builtin signature (short8 or __bf16x8) across ROCm versions.
struct ABFrag {
  s16x8 v;
  __device__ operator s16x8() const { return v; }
  __device__ operator bf16x8() const { return __builtin_bit_cast(bf16x8, v); }
};

__device__ __forceinline__ f32x4 mfma_bf16(s16x8 a, s16x8 b, f32x4 c) {
  return __builtin_amdgcn_mfma_f32_16x16x32_bf16(ABFrag{a}, ABFrag{b}, c, 0, 0, 0);
}

__device__ __forceinline__ void async16(void* lds, const void* g) {
  __builtin_amdgcn_global_load_lds(
      (__attribute__((address_space(1))) void*)(const_cast<void*>(g)),
      (__attribute__((address_space(3))) void*)lds, 16, 0, 0);
}

// ================= fused 3-layer radix selection (LDS histograms) =================
// meta per layer (8 u32): [0]=selA(10b) [1]=r1 [2]=selB(12b) [3]=r2 [4]=candCount
// NOTE (R7 lesson): never histogram via scattered GLOBAL atomics on gfx950 —
// they write through to HBM (~1 GB traffic, 10x slowdown). LDS bins only.

// Pass 1: 10-bit prefix histogram. blockIdx.y = layer (layer-parallel, no
// sequential 3-layer loop). 8-way replicated bins (rep = tid&7): a wave's ~8
// hot-bin lanes spread 1-per-replica -> no same-address serialization.
// Layer 0 blocks also do the x->bf16 convert (balances their smaller hist work).
__global__ void hist1_k(const float4* __restrict__ x, ushort4* __restrict__ xb, int xn4,
                        const uint4* __restrict__ sa, int na,
                        const uint4* __restrict__ sb, int nb,
                        const uint4* __restrict__ sc, int nc,
                        u32* __restrict__ gh) {
  __shared__ u32 h[NB1 * 8];  // 32KB: [bin][replica]
  const int l = blockIdx.y;
  for (int i = threadIdx.x; i < NB1 * 8; i += blockDim.x) h[i] = 0;
  __syncthreads();
  int stride = gridDim.x * blockDim.x;
  if (l == 0) {
    for (int i = blockIdx.x * blockDim.x + threadIdx.x; i < xn4; i += stride) {
      float4 v = x[i];
      ushort4 o;
      o.x = f2bf(v.x); o.y = f2bf(v.y); o.z = f2bf(v.z); o.w = f2bf(v.w);
      xb[i] = o;
    }
  }
  const uint4* s = (l == 0) ? sa : (l == 1 ? sb : sc);
  const int n4 = (l == 0) ? na : (l == 1 ? nb : nc);
  u32* hl = &h[threadIdx.x & 7];
  for (int i = blockIdx.x * blockDim.x + threadIdx.x; i < n4; i += stride) {
    uint4 v = s[i];
    atomicAdd(&hl[((v.x & KEYMASK) >> 21) * 8], 1u);
    atomicAdd(&hl[((v.y & KEYMASK) >> 21) * 8], 1u);
    atomicAdd(&hl[((v.z & KEYMASK) >> 21) * 8], 1u);
    atomicAdd(&hl[((v.w & KEYMASK) >> 21) * 8], 1u);
  }
  __syncthreads();
  for (int i = threadIdx.x; i < NB1; i += blockDim.x) {
    u32 c = 0;
#pragma unroll
    for (int r = 0; r < 8; ++r) c += h[i * 8 + r];
    if (c) atomicAdd(&gh[l * NB1 + i], c);
  }
}

// Pass 2: 12-bit sub-histogram (bits 20..9) of elements whose 10-bit prefix
// == selA. blockIdx.y = layer. Filtered atomics are ~uniform over sub-bins
// (mantissa bits) -> no replication needed; 16KB LDS.
__global__ void hist2_k(const uint4* __restrict__ sa, int na,
                        const uint4* __restrict__ sb, int nb,
                        const uint4* __restrict__ sc, int nc,
                        u32* __restrict__ gh, const u32* __restrict__ meta) {
  __shared__ u32 h[NB2];  // 16KB
  const int l = blockIdx.y;
  for (int i = threadIdx.x; i < NB2; i += blockDim.x) h[i] = 0;
  __syncthreads();
  const uint4* s = (l == 0) ? sa : (l == 1 ? sb : sc);
  const int n4 = (l == 0) ? na : (l == 1 ? nb : nc);
  const u32 selA = meta[l * 8 + 0];
  int stride = gridDim.x * blockDim.x;
  for (int i = blockIdx.x * blockDim.x + threadIdx.x; i < n4; i += stride) {
    uint4 v = s[i];
    u32 k;
    k = v.x & KEYMASK; if ((k >> 21) == selA) atomicAdd(&h[(k >> 9) & 0xfffu], 1u);
    k = v.y & KEYMASK; if ((k >> 21) == selA) atomicAdd(&h[(k >> 9) & 0xfffu], 1u);
    k = v.z & KEYMASK; if ((k >> 21) == selA) atomicAdd(&h[(k >> 9) & 0xfffu], 1u);
    k = v.w & KEYMASK; if ((k >> 21) == selA) atomicAdd(&h[(k >> 9) & 0xfffu], 1u);
  }
  __syncthreads();
  for (int i = threadIdx.x; i < NB2; i += blockDim.x) {
    u32 c = h[i];
    if (c) atomicAdd(&gh[l * NB2 + i], c);
  }
}

template <int STAGE>
__global__ void select_k(const u32* __restrict__ hist, u32* __restrict__ meta,
                         u32 r0, u32 r1, u32 r2) {
  const int l = blockIdx.x;
  const int nbins = (STAGE == 1) ? NB1 : NB2;
  const u32* hl = hist + l * nbins;
  __shared__ u32 part[256];
  int tid = threadIdx.x;
  int chunk = nbins >> 8;
  u32 sm = 0;
  for (int i = tid * chunk; i < (tid + 1) * chunk; ++i) sm += hl[i];
  part[tid] = sm;
  __syncthreads();
  if (tid == 0) {
    u32 r = (STAGE == 1) ? (l == 0 ? r0 : (l == 1 ? r1 : r2)) : meta[l * 8 + 1];
    u32 c = 0; int t = 0;
    for (; t < 256; ++t) { if (c + part[t] > r) break; c += part[t]; }
    u32 rr = r - c;
    int bin = t * chunk;
    for (;;) { u32 hv = hl[bin]; if (rr < hv) break; rr -= hv; ++bin; }
    if (STAGE == 1) { meta[l * 8 + 0] = (u32)bin; meta[l * 8 + 1] = rr; }
    else           { meta[l * 8 + 2] = (u32)bin; meta[l * 8 + 3] = rr; }
  }
}

// Fused mask+cast build: 22-bit prefix > t22 -> bf16(w); < -> 0; == -> 0 + candidate.
// i in [n4, n4pad): write zeros (pad rows for the N=1000->1024 GEMM).
__global__ void build_k(const float4* __restrict__ w, const uint4* __restrict__ s,
                        ushort4* __restrict__ wb, int n4, int n4pad,
                        u32* __restrict__ meta, uint2* __restrict__ cand) {
  u32 t22 = (meta[0] << 12) | meta[2];
  int stride = gridDim.x * blockDim.x;
  for (int i = blockIdx.x * blockDim.x + threadIdx.x; i < n4pad; i += stride) {
    if (i >= n4) { wb[i] = make_ushort4(0, 0, 0, 0); continue; }
    uint4 sv = s[i];
    float4 wv = w[i];
    u32 k0 = sv.x & KEYMASK, k1 = sv.y & KEYMASK, k2 = sv.z & KEYMASK, k3 = sv.w & KEYMASK;
    ushort4 o;
    o.x = ((k0 >> 9) > t22) ? f2bf(wv.x) : (u16)0;
    o.y = ((k1 >> 9) > t22) ? f2bf(wv.y) : (u16)0;
    o.z = ((k2 >> 9) > t22) ? f2bf(wv.z) : (u16)0;
    o.w = ((k3 >> 9) > t22) ? f2bf(wv.w) : (u16)0;
    wb[i] = o;
    u32 base = (u32)i * 4u;
    if ((k0 >> 9) == t22) { u32 p = atomicAdd(&meta[4], 1u); if (p < CANDCAP) cand[p] = make_uint2(k0, base); }
    if ((k1 >> 9) == t22) { u32 p = atomicAdd(&meta[4], 1u); if (p < CANDCAP) cand[p] = make_uint2(k1, base + 1u); }
    if ((k2 >> 9) == t22) { u32 p = atomicAdd(&meta[4], 1u); if (p < CANDCAP) cand[p] = make_uint2(k2, base + 2u); }
    if ((k3 >> 9) == t22) { u32 p = atomicAdd(&meta[4], 1u); if (p < CANDCAP) cand[p] = make_uint2(k3, base + 3u); }
  }
}

// Exact low-9-bit select among candidates + stable-argsort tie semantics.
__global__ void finalize_k(u16* __restrict__ wb, const float* __restrict__ w,
                           const u32* __restrict__ meta, const uint2* __restrict__ cand) {
  __shared__ u32 h[512];
  __shared__ u32 tie[TIECAP];
  __shared__ u32 tcnt, t9s, qs;
  int tid = threadIdx.x;
  for (int i = tid; i < 512; i += blockDim.x) h[i] = 0;
  if (tid == 0) tcnt = 0;
  __syncthreads();
  u32 m = meta[4]; if (m > CANDCAP) m = CANDCAP;
  for (u32 i = tid; i < m; i += blockDim.x) atomicAdd(&h[cand[i].x & 0x1ffu], 1u);
  __syncthreads();
  if (tid == 0) {
    u32 r = meta[3];
    u32 c = 0; int bin = 0;
    for (;;) { u32 hv = h[bin]; if (c + hv > r) break; c += hv; ++bin; }
    t9s = (u32)bin; qs = r - c;
  }
  __syncthreads();
  u32 t9 = t9s, q = qs;
  for (u32 i = tid; i < m; i += blockDim.x) {
    uint2 cd = cand[i];
    u32 k9 = cd.x & 0x1ffu;
    if (k9 > t9) wb[cd.y] = f2bf(w[cd.y]);
    else if (k9 == t9) { u32 p = atomicAdd(&tcnt, 1u); if (p < TIECAP) tie[p] = cd.y; }
  }
  __syncthreads();
  u32 tc = tcnt; if (tc > TIECAP) tc = TIECAP;
  for (u32 i = tid; i < tc; i += blockDim.x) {
    u32 my = tie[i];
    u32 rk = 0;
    for (u32 j = 0; j < tc; ++j) rk += (tie[j] < my) ? 1u : 0u;
    if (rk >= q) wb[my] = f2bf(w[my]);
  }
}

// ======== 256x256 GEMM, BK=64, 8 waves, 4-phase counted-vmcnt pipeline ========
// R4 schedule (best measured: 128.6us / 45% MfmaUtil on 4096^3) — FROZEN.
// A LDS: chunk q = LDS rows q*64.., global rows half*128+q*32+r. B: 4 col chunks.
// XOR-swizzle per 16B granule (g^(R&7)); linear LDS dest + inverse-swizzled src.
// Stage: ph0: A3(t+1)->p^1 | ph1: A0,B0(t+2) | ph2: A1,B1 | ph3: A2,B2,B3.
// Waits: vmcnt(8)@ph0 (tile t minus A3 landed), vmcnt(12)@ph3 (A3(t) landed).
__global__ __launch_bounds__(512) void gemm256(
    const u16* __restrict__ A, const u16* __restrict__ B,
    const float* __restrict__ bias, u16* __restrict__ C,
    int N, int K) {
  __shared__ __align__(16) u16 As[2][256 * 64];
  __shared__ __align__(16) u16 Bs[2][256 * 64];
  const int tid = threadIdx.x;
  const int lane = tid & 63;
  const int wv = tid >> 6;
  const int wm = wv >> 2;        // 0..1
  const int wn = wv & 3;         // 0..3
  const int fr = lane & 15;
  const int fkg = lane >> 4;     // 0..3
  const long brow = (long)blockIdx.y * 256;
  const long bcol = (long)blockIdx.x * 256;

  const int sr6 = tid >> 3;                       // 0..63
  const int sgr = ((tid & 7) ^ (sr6 & 7)) << 3;   // inverse-swizzled src elem offset
  const int ha = tid >> 8;                        // A half (0/1)
  const int ra = sr6 & 31;                        // A row within quarter
  const u16* pAq[4];
  const u16* pBc[4];
#pragma unroll
  for (int q = 0; q < 4; ++q)
    pAq[q] = A + (size_t)(brow + ha * 128 + q * 32 + ra) * (size_t)K + sgr;
#pragma unroll
  for (int c = 0; c < 4; ++c)
    pBc[c] = B + (size_t)(bcol + c * 64 + sr6) * (size_t)K + sgr;

  f32x4 acc[8][4] = {};
  s16x8 bfr[4][2];

  const int swz0 = ((0 + fkg) ^ (fr & 7)) * 16;
  const int swz1 = ((4 + fkg) ^ (fr & 7)) * 16;

  const int aRowBase = wm * 32 + fr;
  const int bRowBase = wn * 64 + fr;

  // ---- prologue: t0 {A0,A1,A2,B0..B3,A3}, t1 {A0,A1,A2,B0..B3} ----
  {
    char* a0 = (char*)&As[0][0] + wv * 1024;
    char* b0 = (char*)&Bs[0][0] + wv * 1024;
    async16(a0 + 0 * 8192, pAq[0]); async16(a0 + 1 * 8192, pAq[1]); async16(a0 + 2 * 8192, pAq[2]);
    async16(b0 + 0 * 8192, pBc[0]); async16(b0 + 1 * 8192, pBc[1]);
    async16(b0 + 2 * 8192, pBc[2]); async16(b0 + 3 * 8192, pBc[3]);
    async16(a0 + 3 * 8192, pAq[3]);
    char* a1 = (char*)&As[1][0] + wv * 1024;
    char* b1 = (char*)&Bs[1][0] + wv * 1024;
    async16(a1 + 0 * 8192, pAq[0] + 64); async16(a1 + 1 * 8192, pAq[1] + 64); async16(a1 + 2 * 8192, pAq[2] + 64);
    async16(b1 + 0 * 8192, pBc[0] + 64); async16(b1 + 1 * 8192, pBc[1] + 64);
    async16(b1 + 2 * 8192, pBc[2] + 64); async16(b1 + 3 * 8192, pBc[3] + 64);
  }

  const int NT = K >> 6;   // requires K >= 128

  for (int t = 0; t < NT; ++t) {
    const int p = t & 1;
    const char* Ab = (const char*)&As[p][0];
    const char* Bb = (const char*)&Bs[p][0];
    char* sA = (char*)&As[p][0] + wv * 1024;
    char* sB = (char*)&Bs[p][0] + wv * 1024;
    char* sAo = (char*)&As[p ^ 1][0] + wv * 1024;
    const int k1 = (t + 1 < NT ? t + 1 : 0) << 6;
    const int k2 = (t + 2 < NT ? t + 2 : 0) << 6;

    // ---------------- phase 0 ----------------
    asm volatile("s_waitcnt vmcnt(8)" ::: "memory");
    __builtin_amdgcn_sched_barrier(0);
    __builtin_amdgcn_s_barrier();
    __builtin_amdgcn_sched_barrier(0);
    {
#pragma unroll
      for (int nf = 0; nf < 4; ++nf) {
        const char* rb = Bb + (bRowBase + nf * 16) * 128;
        bfr[nf][0] = *(const s16x8*)(rb + swz0);
        bfr[nf][1] = *(const s16x8*)(rb + swz1);
      }
      s16x8 a_[2][2];
#pragma unroll
      for (int j = 0; j < 2; ++j) {
        const char* rb = Ab + (0 * 64 + aRowBase + j * 16) * 128;
        a_[j][0] = *(const s16x8*)(rb + swz0);
        a_[j][1] = *(const s16x8*)(rb + swz1);
      }
      async16(sAo + 3 * 8192, pAq[3] + k1);
      __builtin_amdgcn_s_setprio(1);
#pragma unroll
      for (int j = 0; j < 2; ++j)
#pragma unroll
        for (int kk = 0; kk < 2; ++kk)
#pragma unroll
          for (int nf = 0; nf < 4; ++nf)
            acc[j][nf] = mfma_bf16(a_[j][kk], bfr[nf][kk], acc[j][nf]);
      __builtin_amdgcn_s_setprio(0);
    }

    // ---------------- phase 1 ----------------
    __builtin_amdgcn_sched_barrier(0);
    __builtin_amdgcn_s_barrier();
    __builtin_amdgcn_sched_barrier(0);
    {
      s16x8 a_[2][2];
#pragma unroll
      for (int j = 0; j < 2; ++j) {
        const char* rb = Ab + (1 * 64 + aRowBase + j * 16) * 128;
        a_[j][0] = *(const s16x8*)(rb + swz0);
        a_[j][1] = *(const s16x8*)(rb + swz1);
      }
      async16(sA + 0 * 8192, pAq[0] + k2);
      async16(sB + 0 * 8192, pBc[0] + k2);
      __builtin_amdgcn_s_setprio(1);
#pragma unroll
      for (int j = 0; j < 2; ++j)
#pragma unroll
        for (int kk = 0; kk < 2; ++kk)
#pragma unroll
          for (int nf = 0; nf < 4; ++nf)
            acc[2 + j][nf] = mfma_bf16(a_[j][kk], bfr[nf][kk], acc[2 + j][nf]);
      __builtin_amdgcn_s_setprio(0);
    }

    // ---------------- phase 2 ----------------
    __builtin_amdgcn_sched_barrier(0);
    __builtin_amdgcn_s_barrier();
    __builtin_amdgcn_sched_barrier(0);
    {
      s16x8 a_[2][2];
#pragma unroll
      for (int j = 0; j < 2; ++j) {
        const char* rb = Ab + (2 * 64 + aRowBase + j * 16) * 128;
        a_[j][0] = *(const s16x8*)(rb + swz0);
        a_[j][1] = *(const s16x8*)(rb + swz1);
      }
      async16(sA + 1 * 8192, pAq[1] + k2);
      async16(sB + 1 * 8192, pBc[1] + k2);
      __builtin_amdgcn_s_setprio(1);
#pragma unroll
      for (int j = 0; j < 2; ++j)
#pragma unroll
        for (int kk = 0; kk < 2; ++kk)
#pragma unroll
          for (int nf = 0; nf < 4; ++nf)
            acc[4 + j][nf] = mfma_bf16(a_[j][kk], bfr[nf][kk], acc[4 + j][nf]);
      __builtin_amdgcn_s_setprio(0);
    }

    // ---------------- phase 3 ----------------
    asm volatile("s_waitcnt vmcnt(12)" ::: "memory");
    __builtin_amdgcn_sched_barrier(0);
    __builtin_amdgcn_s_barrier();
    __builtin_amdgcn_sched_barrier(0);
    {
      s16x8 a_[2][2];
#pragma unroll
      for (int j = 0; j < 2; ++j) {
        const char* rb = Ab + (3 * 64 + aRowBase + j * 16) * 128;
        a_[j][0] = *(const s16x8*)(rb + swz0);
        a_[j][1] = *(const s16x8*)(rb + swz1);
      }
      async16(sA + 2 * 8192, pAq[2] + k2);
      async16(sB + 2 * 8192, pBc[2] + k2);
      async16(sB + 3 * 8192, pBc[3] + k2);
      __builtin_amdgcn_s_setprio(1);
#pragma unroll
      for (int j = 0; j < 2; ++j)
#pragma unroll
        for (int kk = 0; kk < 2; ++kk)
#pragma unroll
          for (int nf = 0; nf < 4; ++nf)
            acc[6 + j][nf] = mfma_bf16(a_[j][kk], bfr[nf][kk], acc[6 + j][nf]);
      __builtin_amdgcn_s_setprio(0);
    }
  }

  asm volatile("s_waitcnt vmcnt(0)" ::: "memory");  // drain clamped tail stages

  // epilogue: C/D layout col=lane&15, row=(lane>>4)*4+i (m89-verified)
#pragma unroll
  for (int nf = 0; nf < 4; ++nf) {
    const long col = bcol + wn * 64 + nf * 16 + fr;
    const float bv = bias[col];
#pragma unroll
    for (int mf = 0; mf < 8; ++mf) {
      const long row0 = brow + wm * 128 + mf * 16 + fkg * 4;
#pragma unroll
      for (int i = 0; i < 4; ++i) {
        float v = fmaxf(acc[mf][nf][i] + bv, 0.0f);
        C[(row0 + i) * (long)N + col] = f2bf(v);
      }
    }
  }
}

// ---------------- 128x128 GEMM (layer 3: N=1000->1024) ----------------
template <int RELU, int CBF16>
__global__ __launch_bounds__(256) void gemm_bt(
    const u16* __restrict__ A, const u16* __restrict__ B,
    const float* __restrict__ bias, void* __restrict__ Cv,
    int Ntrue, int K) {
  __shared__ __align__(16) u16 As[128 * 32];
  __shared__ __align__(16) u16 Bs[128 * 32];
  const int tid = threadIdx.x;
  const int lane = tid & 63;
  const int wv = tid >> 6;
  const long brow = (long)blockIdx.y * 128;
  const long bcol = (long)blockIdx.x * 128;
  const int wm = (wv >> 1) * 64;
  const int wn = (wv & 1) * 64;

  const u16* gA0 = A + (brow + (tid >> 2)) * (long)K + (tid & 3) * 8;
  const u16* gA1 = gA0 + (size_t)64 * K;
  const u16* gB0 = B + (bcol + (tid >> 2)) * (long)K + (tid & 3) * 8;
  const u16* gB1 = gB0 + (size_t)64 * K;
  char* lA0 = (char*)As + wv * 1024;
  char* lA1 = (char*)As + 4096 + wv * 1024;
  char* lB0 = (char*)Bs + wv * 1024;
  char* lB1 = (char*)Bs + 4096 + wv * 1024;

  f32x4 acc[4][4] = {};
  const int fr = lane & 15;
  const int fk = (lane >> 4) * 8;

  for (int kt = 0; kt < K; kt += 32) {
    async16(lA0, gA0 + kt);
    async16(lA1, gA1 + kt);
    async16(lB0, gB0 + kt);
    async16(lB1, gB1 + kt);
    __syncthreads();
    s16x8 a[4], b[4];
#pragma unroll
    for (int m = 0; m < 4; ++m) a[m] = *(const s16x8*)&As[(wm + m * 16 + fr) * 32 + fk];
#pragma unroll
    for (int n = 0; n < 4; ++n) b[n] = *(const s16x8*)&Bs[(wn + n * 16 + fr) * 32 + fk];
#pragma unroll
    for (int m = 0; m < 4; ++m)
#pragma unroll
      for (int n = 0; n < 4; ++n)
        acc[m][n] = mfma_bf16(a[m], b[n], acc[m][n]);
    __syncthreads();
  }

  const long col0 = bcol + wn + fr;
  const long row0 = brow + wm + ((lane >> 4) << 2);
#pragma unroll
  for (int n = 0; n < 4; ++n) {
    long col = col0 + n * 16;
    if (!CBF16 && col >= Ntrue) continue;
    float bv = bias[col];
#pragma unroll
    for (int m = 0; m < 4; ++m) {
#pragma unroll
      for (int i = 0; i < 4; ++i) {
        float v = acc[m][n][i] + bv;
        if (RELU) v = fmaxf(v, 0.0f);
        long off = (row0 + m * 16 + i) * (long)Ntrue + col;
        if (CBF16) ((u16*)Cv)[off] = f2bf(v);
        else ((float*)Cv)[off] = v;
      }
    }
  }
}

// ---------------- launch ----------------
extern "C" void kernel_launch(void* const* d_in, const int* in_sizes, int n_in,
                              void* d_out, int out_size, void* d_ws, size_t ws_size,
                              hipStream_t stream) {
  const float* x  = (const float*)d_in[0];
  const float* w1 = (const float*)d_in[1];
  const float* s1 = (const float*)d_in[2];
  const float* b1 = (const float*)d_in[3];
  const float* w2 = (const float*)d_in[4];
  const float* s2 = (const float*)d_in[5];
  const float* b2 = (const float*)d_in[6];
  const float* w3 = (const float*)d_in[7];
  const float* s3 = (const float*)d_in[8];
  const float* b3 = (const float*)d_in[9];
  float* out = (float*)d_out;

  const int n1 = 4096 * 2048, n2 = 4096 * 4096, n3 = 1000 * 4096;

  char* ws = (char*)d_ws;
  u32*   meta = (u32*)ws;                  // 3 x 8 u32
  u32*   gh1  = (u32*)(ws + 0x1000);       // 3 x 1024
  u32*   gh2  = (u32*)(ws + 0x4000);       // 3 x 4096, ends 0x10000
  uint2* cand = (uint2*)(ws + 0x10000);    // 3 x 65536 x 8B, ends 0x190000
  u16* Wb = (u16*)(ws + (2l  << 20));      // 32 MiB, reused per layer
  u16* H1 = (u16*)(ws + (34l << 20));      // 32 MiB
  u16* H2 = (u16*)(ws + (66l << 20));      // 32 MiB
  u16* Xb = (u16*)(ws + (66l << 20));      // 16 MiB, aliases H2 (dead before gemm2 writes H2)

  // fused selection: convert + hists + selects for all 3 layers (layer-parallel grids)
  hipMemsetAsync(ws, 0, 0x10000, stream);
  hist1_k<<<dim3(256, 3), 1024, 0, stream>>>((const float4*)x, (ushort4*)Xb, n1 / 4,
                                             (const uint4*)s1, n1 / 4, (const uint4*)s2, n2 / 4,
                                             (const uint4*)s3, n3 / 4, gh1);
  select_k<1><<<3, 256, 0, stream>>>(gh1, meta, (u32)(n1 / 2), (u32)(n2 / 2), (u32)(n3 / 2));
  hist2_k<<<dim3(256, 3), 1024, 0, stream>>>((const uint4*)s1, n1 / 4, (const uint4*)s2, n2 / 4,
                                             (const uint4*)s3, n3 / 4, gh2, meta);
  select_k<2><<<3, 256, 0, stream>>>(gh2, meta, 0, 0, 0);

  // Layer 1: (4096x2048) -> 4096, relu, bf16
  build_k<<<512, 256, 0, stream>>>((const float4*)w1, (const uint4*)s1, (ushort4*)Wb,
                                   n1 / 4, n1 / 4, meta + 0, cand + 0);
  finalize_k<<<1, 1024, 0, stream>>>(Wb, w1, meta + 0, cand + 0);
  gemm256<<<dim3(16, 16), 512, 0, stream>>>(Xb, Wb, b1, H1, 4096, 2048);

  // Layer 2: 4096 -> 4096, relu, bf16
  build_k<<<512, 256, 0, stream>>>((const float4*)w2, (const uint4*)s2, (ushort4*)Wb,
                                   n2 / 4, n2 / 4, meta + 8, cand + CANDCAP);
  finalize_k<<<1, 1024, 0, stream>>>(Wb, w2, meta + 8, cand + CANDCAP);
  gemm256<<<dim3(16, 16), 512, 0, stream>>>(H1, Wb, b2, H2, 4096, 4096);

  // Layer 3: 4096 -> 1000 (rows padded to 1024 inside build_k), fp32 out
  build_k<<<512, 256, 0, stream>>>((const float4*)w3, (const uint4*)s3, (ushort4*)Wb,
                                   n3 / 4, (1024 * 4096) / 4, meta + 16, cand + 2 * CANDCAP);
  finalize_k<<<1, 1024, 0, stream>>>(Wb, w3, meta + 16, cand + 2 * CANDCAP);
  gemm_bt<0, 0><<<dim3(8, 32), 256, 0, stream>>>(H2, Wb, b3, out, 1000, 4096);
}